// Round 1
// baseline (238.493 us; speedup 1.0000x reference)
//
#include <hip/hip_runtime.h>

#define D_IN 4096
#define FEAT 4096
#define BATCH 4096
#define MAX_SLOTS 64   // capacity per feature (actual ~50)

// ---------------------------------------------------------------------------
// Kernel 1: zero the per-feature counters (d_ws is poisoned 0xAA every call)
// ---------------------------------------------------------------------------
__global__ void zero_cnt_kernel(unsigned int* __restrict__ cnt) {
    int t = blockIdx.x * blockDim.x + threadIdx.x;
    if (t < FEAT) cnt[t] = 0u;
}

// ---------------------------------------------------------------------------
// Kernel 2: scan w_raw (row-major [D_IN][FEAT]) coalesced; for each positive
// entry append its row index i to feature f's list.
// List layout is j-major quad-packed u16:
//   ushort slot 'pos' of feature f lives at ((pos>>2)*FEAT + f)*4 + (pos&3)
// so the main kernel can read 4 indices per feature with ONE coalesced uint2
// load across lanes (lanes = consecutive f).
// ---------------------------------------------------------------------------
__global__ void build_lists_kernel(const float* __restrict__ w,
                                   unsigned int* __restrict__ cnt,
                                   unsigned short* __restrict__ idx) {
    int t = blockIdx.x * blockDim.x + threadIdx.x;   // one float4 per thread
    float4 v = ((const float4*)w)[t];
    int flat = t * 4;
    float a[4] = {v.x, v.y, v.z, v.w};
#pragma unroll
    for (int c = 0; c < 4; ++c) {
        if (a[c] > 0.0f) {
            int e = flat + c;
            int f = e & (FEAT - 1);
            int i = e >> 12;           // e / FEAT
            unsigned int pos = atomicAdd(&cnt[f], 1u);
            if (pos < MAX_SLOTS) {
                idx[((pos >> 2) * FEAT + f) * 4 + (pos & 3)] = (unsigned short)i;
            }
        }
    }
}

// ---------------------------------------------------------------------------
// Kernel 3: the gather-sum.
// Each block owns 4 batch rows, staged TRANSPOSED in LDS: xt[i] = float4 of
// {x[b0..b0+3][i]} so each gathered index costs one ds_read_b128 covering 4
// batch rows. Each thread walks 8 feature columns (4096 / 512), accumulating
// |S_f| ~ 50 gathers into a float4 accumulator, then stores 4 coalesced fp32.
// LDS = 64KB -> 2 blocks/CU (128KB of 160KB), 16 waves/CU.
// ---------------------------------------------------------------------------
__device__ __forceinline__ void acc4(float4& a, const float4& v) {
    a.x += v.x; a.y += v.y; a.z += v.z; a.w += v.w;
}

__global__ __launch_bounds__(512, 4)
void gather_kernel(const float* __restrict__ x,
                   const unsigned int* __restrict__ cnt,
                   const uint2* __restrict__ q,      // quad-packed u16 indices
                   float* __restrict__ out) {
    __shared__ float4 xt[D_IN];                      // 64 KB
    float* xs = (float*)xt;
    const int tid = threadIdx.x;
    const int b0  = blockIdx.x * 4;

    // Stage 4 rows transposed. Global loads coalesced (b32 across lanes);
    // LDS writes are stride-16B (8-way bank aliasing) but only 64KB total.
#pragma unroll
    for (int r = 0; r < 4; ++r) {
        const float* row = x + (size_t)(b0 + r) * D_IN;
        for (int i = tid; i < D_IN; i += 512) {
            xs[i * 4 + r] = row[i];
        }
    }
    __syncthreads();

    for (int f = tid; f < FEAT; f += 512) {
        int n = (int)cnt[f];
        if (n > MAX_SLOTS) n = MAX_SLOTS;
        const uint2* qp = q + f;

        float4 a0 = {0.f, 0.f, 0.f, 0.f};
        float4 a1 = {0.f, 0.f, 0.f, 0.f};

        int nq = n >> 2;
        for (int j = 0; j < nq; ++j) {
            uint2 p = qp[(size_t)j * FEAT];          // 4 indices, coalesced
            float4 v0 = xt[p.x & 0xFFFFu];
            float4 v1 = xt[p.x >> 16];
            float4 v2 = xt[p.y & 0xFFFFu];
            float4 v3 = xt[p.y >> 16];
            acc4(a0, v0); acc4(a1, v1); acc4(a0, v2); acc4(a1, v3);
        }
        int rem = n & 3;
        if (rem) {
            uint2 p = qp[(size_t)nq * FEAT];
            if (rem > 0) { float4 v = xt[p.x & 0xFFFFu]; acc4(a0, v); }
            if (rem > 1) { float4 v = xt[p.x >> 16];     acc4(a1, v); }
            if (rem > 2) { float4 v = xt[p.y & 0xFFFFu]; acc4(a0, v); }
        }

        acc4(a0, a1);
        float* o = out + f;
        o[(size_t)(b0 + 0) * FEAT] = a0.x;
        o[(size_t)(b0 + 1) * FEAT] = a0.y;
        o[(size_t)(b0 + 2) * FEAT] = a0.z;
        o[(size_t)(b0 + 3) * FEAT] = a0.w;
    }
}

// ---------------------------------------------------------------------------
extern "C" void kernel_launch(void* const* d_in, const int* in_sizes, int n_in,
                              void* d_out, int out_size, void* d_ws, size_t ws_size,
                              hipStream_t stream) {
    const float* x = (const float*)d_in[0];      // (BATCH, D_IN) fp32
    const float* w = (const float*)d_in[1];      // (D_IN, FEAT)  fp32
    float* out = (float*)d_out;                  // (BATCH, FEAT) fp32

    // Workspace layout: [cnt: 4096 u32 = 16KB][idx: 4096*64 u16 = 512KB]
    unsigned int*   cnt = (unsigned int*)d_ws;
    unsigned short* idx = (unsigned short*)((char*)d_ws + FEAT * sizeof(unsigned int));

    zero_cnt_kernel<<<(FEAT + 255) / 256, 256, 0, stream>>>(cnt);

    // D_IN*FEAT/4 float4 elements, 256 threads each
    build_lists_kernel<<<(D_IN * FEAT / 4) / 256, 256, 0, stream>>>(w, cnt, idx);

    gather_kernel<<<BATCH / 4, 512, 0, stream>>>(x, cnt, (const uint2*)idx, out);
}

// Round 2
// 223.983 us; speedup vs baseline: 1.0648x; 1.0648x over previous
//
#include <hip/hip_runtime.h>

#define D_IN 4096
#define FEAT 4096
#define BATCH 4096
#define MAX_SLOTS 64   // capacity per feature (actual ~50, ties can give 51)

// ---------------------------------------------------------------------------
// Kernel 1: zero the per-feature counters (d_ws is poisoned 0xAA every call)
// ---------------------------------------------------------------------------
__global__ void zero_cnt_kernel(unsigned int* __restrict__ cnt) {
    int t = blockIdx.x * blockDim.x + threadIdx.x;
    if (t < FEAT) cnt[t] = 0u;
}

// ---------------------------------------------------------------------------
// Kernel 2: scan w_raw (row-major [D_IN][FEAT]) coalesced; for each positive
// entry append its row index i to feature f's list.
// Quad-packed u16 layout: slot 'pos' of feature f lives at ushort offset
// ((pos>>2)*FEAT + f)*4 + (pos&3), so 4 indices = one uint2, coalesced
// across lanes (consecutive f).
// ---------------------------------------------------------------------------
__global__ void build_lists_kernel(const float* __restrict__ w,
                                   unsigned int* __restrict__ cnt,
                                   unsigned short* __restrict__ idx) {
    int t = blockIdx.x * blockDim.x + threadIdx.x;   // one float4 per thread
    float4 v = ((const float4*)w)[t];
    int flat = t * 4;
    float a[4] = {v.x, v.y, v.z, v.w};
#pragma unroll
    for (int c = 0; c < 4; ++c) {
        if (a[c] > 0.0f) {
            int e = flat + c;
            int f = e & (FEAT - 1);
            int i = e >> 12;           // e / FEAT
            unsigned int pos = atomicAdd(&cnt[f], 1u);
            if (pos < MAX_SLOTS) {
                idx[((pos >> 2) * FEAT + f) * 4 + (pos & 3)] = (unsigned short)i;
            }
        }
    }
}

// ---------------------------------------------------------------------------
// Kernel 3: gather-sum, bf16-staged, 8 batch rows per block.
// LDS xt[i] = uint4 = 8 bf16 = rows b0..b0+7 of column i. One ds_read_b128
// per gathered index serves 8 batch rows (2 B/row vs 4 B/row in R1).
// 512 blocks x 512 threads; 64 KB LDS -> 2 blocks/CU, 16 waves/CU.
// Accumulate in fp32 (bf16 only in the staged operand).
// ---------------------------------------------------------------------------
__device__ __forceinline__ unsigned short f2bf(float f) {
    unsigned u = __float_as_uint(f);
    unsigned r = u + 0x7fffu + ((u >> 16) & 1u);   // round-to-nearest-even
    return (unsigned short)(r >> 16);
}

__device__ __forceinline__ void acc8(float* a, uint4 v) {
    a[0] += __uint_as_float(v.x << 16);
    a[1] += __uint_as_float(v.x & 0xffff0000u);
    a[2] += __uint_as_float(v.y << 16);
    a[3] += __uint_as_float(v.y & 0xffff0000u);
    a[4] += __uint_as_float(v.z << 16);
    a[5] += __uint_as_float(v.z & 0xffff0000u);
    a[6] += __uint_as_float(v.w << 16);
    a[7] += __uint_as_float(v.w & 0xffff0000u);
}

__global__ __launch_bounds__(512, 4)
void gather_kernel(const float* __restrict__ x,
                   const unsigned int* __restrict__ cnt,
                   const uint2* __restrict__ q,      // quad-packed u16 indices
                   float* __restrict__ out) {
    __shared__ uint4 xt[D_IN];                       // 64 KB
    const int tid = threadIdx.x;
    const int b0  = blockIdx.x * 8;

    // Stage 8 rows, transposed + bf16-packed. Each thread owns col-groups of
    // 4: loads float4 from each of 8 rows (coalesced across lanes), packs
    // each column's 8 rows into a uint4, one ds_write_b128 per column.
    for (int g = tid; g < D_IN / 4; g += 512) {
        float4 r[8];
#pragma unroll
        for (int rr = 0; rr < 8; ++rr) {
            r[rr] = ((const float4*)(x + (size_t)(b0 + rr) * D_IN))[g];
        }
#pragma unroll
        for (int c = 0; c < 4; ++c) {
            const float* rp0 = (const float*)&r[0];
            const float* rp1 = (const float*)&r[1];
            const float* rp2 = (const float*)&r[2];
            const float* rp3 = (const float*)&r[3];
            const float* rp4 = (const float*)&r[4];
            const float* rp5 = (const float*)&r[5];
            const float* rp6 = (const float*)&r[6];
            const float* rp7 = (const float*)&r[7];
            uint4 p;
            p.x = (unsigned)f2bf(rp0[c]) | ((unsigned)f2bf(rp1[c]) << 16);
            p.y = (unsigned)f2bf(rp2[c]) | ((unsigned)f2bf(rp3[c]) << 16);
            p.z = (unsigned)f2bf(rp4[c]) | ((unsigned)f2bf(rp5[c]) << 16);
            p.w = (unsigned)f2bf(rp6[c]) | ((unsigned)f2bf(rp7[c]) << 16);
            xt[g * 4 + c] = p;
        }
    }
    __syncthreads();

    for (int f = tid; f < FEAT; f += 512) {
        int n = (int)cnt[f];
        if (n > MAX_SLOTS) n = MAX_SLOTS;
        const uint2* qp = q + f;

        float a[8] = {0.f, 0.f, 0.f, 0.f, 0.f, 0.f, 0.f, 0.f};

        int nq = n >> 2;
        for (int j = 0; j < nq; ++j) {
            uint2 p = qp[(size_t)j * FEAT];          // 4 indices, coalesced
            uint4 v0 = xt[p.x & 0xFFFFu];
            uint4 v1 = xt[p.x >> 16];
            uint4 v2 = xt[p.y & 0xFFFFu];
            uint4 v3 = xt[p.y >> 16];
            acc8(a, v0); acc8(a, v1); acc8(a, v2); acc8(a, v3);
        }
        int rem = n & 3;
        if (rem) {
            uint2 p = qp[(size_t)nq * FEAT];
            if (rem > 0) acc8(a, xt[p.x & 0xFFFFu]);
            if (rem > 1) acc8(a, xt[p.x >> 16]);
            if (rem > 2) acc8(a, xt[p.y & 0xFFFFu]);
        }

        float* o = out + f;
#pragma unroll
        for (int rr = 0; rr < 8; ++rr) {
            o[(size_t)(b0 + rr) * FEAT] = a[rr];     // coalesced across lanes
        }
    }
}

// ---------------------------------------------------------------------------
extern "C" void kernel_launch(void* const* d_in, const int* in_sizes, int n_in,
                              void* d_out, int out_size, void* d_ws, size_t ws_size,
                              hipStream_t stream) {
    const float* x = (const float*)d_in[0];      // (BATCH, D_IN) fp32
    const float* w = (const float*)d_in[1];      // (D_IN, FEAT)  fp32
    float* out = (float*)d_out;                  // (BATCH, FEAT) fp32

    // Workspace: [cnt: 4096 u32 = 16KB][idx: 4096*64 u16 = 512KB]
    unsigned int*   cnt = (unsigned int*)d_ws;
    unsigned short* idx = (unsigned short*)((char*)d_ws + FEAT * sizeof(unsigned int));

    zero_cnt_kernel<<<(FEAT + 255) / 256, 256, 0, stream>>>(cnt);

    build_lists_kernel<<<(D_IN * FEAT / 4) / 256, 256, 0, stream>>>(w, cnt, idx);

    gather_kernel<<<BATCH / 8, 512, 0, stream>>>(x, cnt, (const uint2*)idx, out);
}

// Round 3
// 217.486 us; speedup vs baseline: 1.0966x; 1.0299x over previous
//
#include <hip/hip_runtime.h>
#include <hip/hip_fp16.h>

#define D_IN 4096
#define FEAT 4096
#define BATCH 4096
#define MAX_SLOTS 64   // capacity per feature (actual ~50, ties can give 51)

typedef _Float16 half2_t __attribute__((ext_vector_type(2)));

// ---------------------------------------------------------------------------
// Kernel 1: scan w_raw (row-major [D_IN][FEAT]) coalesced; for each positive
// entry append its row index i to feature f's list.
// Quad-packed u16 layout: slot 'pos' of feature f lives at ushort offset
// ((pos>>2)*FEAT + f)*4 + (pos&3), so 4 indices = one uint2, coalesced
// across lanes (consecutive f).
// ---------------------------------------------------------------------------
__global__ void build_lists_kernel(const float* __restrict__ w,
                                   unsigned int* __restrict__ cnt,
                                   unsigned short* __restrict__ idx) {
    int t = blockIdx.x * blockDim.x + threadIdx.x;   // one float4 per thread
    float4 v = ((const float4*)w)[t];
    int flat = t * 4;
    float a[4] = {v.x, v.y, v.z, v.w};
#pragma unroll
    for (int c = 0; c < 4; ++c) {
        if (a[c] > 0.0f) {
            int e = flat + c;
            int f = e & (FEAT - 1);
            int i = e >> 12;           // e / FEAT
            unsigned int pos = atomicAdd(&cnt[f], 1u);
            if (pos < MAX_SLOTS) {
                idx[((pos >> 2) * FEAT + f) * 4 + (pos & 3)] = (unsigned short)i;
            }
        }
    }
}

// ---------------------------------------------------------------------------
// extract-low/high fp16 + fp32 accumulate in ONE instruction via
// v_dot2_f32_f16 where available.
// ---------------------------------------------------------------------------
__device__ __forceinline__ float acc_h2(unsigned u, half2_t sel, float acc) {
#if __has_builtin(__builtin_amdgcn_fdot2)
    return __builtin_amdgcn_fdot2(__builtin_bit_cast(half2_t, u), sel, acc, false);
#else
    half2_t h = __builtin_bit_cast(half2_t, u);
    return acc + (float)h[0] * (float)sel[0] + (float)h[1] * (float)sel[1];
#endif
}

// ---------------------------------------------------------------------------
// Kernel 2: gather-sum. 4 batch rows per block, fp16-packed transposed in
// LDS: xt[i] = uint2 = 4 fp16 = rows b0..b0+3 of column i.  32 KB LDS ->
// 4 blocks/CU (128 of 160 KB), 1024 blocks x 8 waves = full 32 waves/CU.
// One ds_read_b64 per gathered index serves 4 rows; each row accumulated
// with a single v_dot2_f32_f16. fp32 accumulators.
// ---------------------------------------------------------------------------
__global__ __launch_bounds__(512, 8)
void gather_kernel(const float* __restrict__ x,
                   const unsigned int* __restrict__ cnt,
                   const uint2* __restrict__ q,      // quad-packed u16 indices
                   float* __restrict__ out) {
    __shared__ uint2 xt[D_IN];                       // 32 KB
    const int tid = threadIdx.x;
    const int b0  = blockIdx.x * 4;
    const float* xb = x + (size_t)b0 * D_IN;

    // Stage 4 rows transposed + fp16 RNE packed. Global b32 loads coalesced
    // across lanes; ds_write_b64 stride-8B (4-way bank alias, tiny volume).
    for (int c = tid; c < D_IN; c += 512) {
        float r0 = xb[c];
        float r1 = xb[c + D_IN];
        float r2 = xb[c + 2 * D_IN];
        float r3 = xb[c + 3 * D_IN];
        __half2 lo = __floats2half2_rn(r0, r1);
        __half2 hi = __floats2half2_rn(r2, r3);
        uint2 v;
        v.x = *(unsigned*)&lo;
        v.y = *(unsigned*)&hi;
        xt[c] = v;
    }
    __syncthreads();

    const half2_t SEL0 = {(_Float16)1.0f, (_Float16)0.0f};
    const half2_t SEL1 = {(_Float16)0.0f, (_Float16)1.0f};

    for (int f = tid; f < FEAT; f += 512) {
        int n = (int)cnt[f];
        if (n > MAX_SLOTS) n = MAX_SLOTS;
        const uint2* qp = q + f;

        float a0 = 0.f, a1 = 0.f, a2 = 0.f, a3 = 0.f;

        int nq = n >> 2;
        for (int j = 0; j < nq; ++j) {
            uint2 p = qp[(size_t)j * FEAT];          // 4 indices, coalesced
            uint2 v0 = xt[p.x & 0xFFFFu];
            uint2 v1 = xt[p.x >> 16];
            uint2 v2 = xt[p.y & 0xFFFFu];
            uint2 v3 = xt[p.y >> 16];
            a0 = acc_h2(v0.x, SEL0, a0); a1 = acc_h2(v0.x, SEL1, a1);
            a2 = acc_h2(v0.y, SEL0, a2); a3 = acc_h2(v0.y, SEL1, a3);
            a0 = acc_h2(v1.x, SEL0, a0); a1 = acc_h2(v1.x, SEL1, a1);
            a2 = acc_h2(v1.y, SEL0, a2); a3 = acc_h2(v1.y, SEL1, a3);
            a0 = acc_h2(v2.x, SEL0, a0); a1 = acc_h2(v2.x, SEL1, a1);
            a2 = acc_h2(v2.y, SEL0, a2); a3 = acc_h2(v2.y, SEL1, a3);
            a0 = acc_h2(v3.x, SEL0, a0); a1 = acc_h2(v3.x, SEL1, a1);
            a2 = acc_h2(v3.y, SEL0, a2); a3 = acc_h2(v3.y, SEL1, a3);
        }
        int rem = n & 3;
        if (rem) {
            uint2 p = qp[(size_t)nq * FEAT];
            unsigned i0 = p.x & 0xFFFFu, i1 = p.x >> 16, i2 = p.y & 0xFFFFu;
            if (rem > 0) { uint2 v = xt[i0];
                a0 = acc_h2(v.x, SEL0, a0); a1 = acc_h2(v.x, SEL1, a1);
                a2 = acc_h2(v.y, SEL0, a2); a3 = acc_h2(v.y, SEL1, a3); }
            if (rem > 1) { uint2 v = xt[i1];
                a0 = acc_h2(v.x, SEL0, a0); a1 = acc_h2(v.x, SEL1, a1);
                a2 = acc_h2(v.y, SEL0, a2); a3 = acc_h2(v.y, SEL1, a3); }
            if (rem > 2) { uint2 v = xt[i2];
                a0 = acc_h2(v.x, SEL0, a0); a1 = acc_h2(v.x, SEL1, a1);
                a2 = acc_h2(v.y, SEL0, a2); a3 = acc_h2(v.y, SEL1, a3); }
        }

        float* o = out + f;
        o[(size_t)(b0 + 0) * FEAT] = a0;             // coalesced across lanes
        o[(size_t)(b0 + 1) * FEAT] = a1;
        o[(size_t)(b0 + 2) * FEAT] = a2;
        o[(size_t)(b0 + 3) * FEAT] = a3;
    }
}

// ---------------------------------------------------------------------------
extern "C" void kernel_launch(void* const* d_in, const int* in_sizes, int n_in,
                              void* d_out, int out_size, void* d_ws, size_t ws_size,
                              hipStream_t stream) {
    const float* x = (const float*)d_in[0];      // (BATCH, D_IN) fp32
    const float* w = (const float*)d_in[1];      // (D_IN, FEAT)  fp32
    float* out = (float*)d_out;                  // (BATCH, FEAT) fp32

    // Workspace: [cnt: 4096 u32 = 16KB][idx: 4096*64 u16 = 512KB]
    unsigned int*   cnt = (unsigned int*)d_ws;
    unsigned short* idx = (unsigned short*)((char*)d_ws + FEAT * sizeof(unsigned int));

    hipMemsetAsync(cnt, 0, FEAT * sizeof(unsigned int), stream);

    build_lists_kernel<<<(D_IN * FEAT / 4) / 256, 256, 0, stream>>>(w, cnt, idx);

    gather_kernel<<<BATCH / 4, 512, 0, stream>>>(x, cnt, (const uint2*)idx, out);
}

// Round 4
// 213.848 us; speedup vs baseline: 1.1152x; 1.0170x over previous
//
#include <hip/hip_runtime.h>
#include <hip/hip_fp16.h>

#define D_IN 4096
#define FEAT 4096
#define BATCH 4096
#define MAX_SLOTS 64   // capacity per feature (actual ~50-51); multiple of 8

typedef _Float16 h2 __attribute__((ext_vector_type(2)));

__device__ __forceinline__ h2 bc(unsigned u) { return __builtin_bit_cast(h2, u); }

// ---------------------------------------------------------------------------
// Kernel 1: scan w_raw (row-major [D_IN][FEAT]) coalesced; append active row
// indices to feature f's list. OCT-packed u16 layout: slot 'pos' of feature f
// lives at ushort offset ((pos>>3)*FEAT + f)*8 + (pos&7), so 8 indices = one
// uint4 load, coalesced across lanes (consecutive f).
// ---------------------------------------------------------------------------
__global__ void build_lists_kernel(const float* __restrict__ w,
                                   unsigned int* __restrict__ cnt,
                                   unsigned short* __restrict__ idx) {
    int t = blockIdx.x * blockDim.x + threadIdx.x;   // one float4 per thread
    float4 v = ((const float4*)w)[t];
    int flat = t * 4;
    float a[4] = {v.x, v.y, v.z, v.w};
#pragma unroll
    for (int c = 0; c < 4; ++c) {
        if (a[c] > 0.0f) {
            int e = flat + c;
            int f = e & (FEAT - 1);
            int i = e >> 12;           // e / FEAT
            unsigned int pos = atomicAdd(&cnt[f], 1u);
            if (pos < MAX_SLOTS) {
                idx[((pos >> 3) * FEAT + f) * 8 + (pos & 7)] = (unsigned short)i;
            }
        }
    }
}

// ---------------------------------------------------------------------------
// Gather one oct (8 indices) from LDS, fp16-pair accumulate.
// Even indices -> A accumulators, odd -> B (2 chains: ILP + halved rounding walk).
// ---------------------------------------------------------------------------
__device__ __forceinline__ void do_oct(uint4 p, const uint2* __restrict__ xt,
                                       h2& A01, h2& A23, h2& B01, h2& B23) {
    uint2 v0 = xt[p.x & 0xFFFFu];
    uint2 v1 = xt[p.x >> 16];
    uint2 v2 = xt[p.y & 0xFFFFu];
    uint2 v3 = xt[p.y >> 16];
    uint2 v4 = xt[p.z & 0xFFFFu];
    uint2 v5 = xt[p.z >> 16];
    uint2 v6 = xt[p.w & 0xFFFFu];
    uint2 v7 = xt[p.w >> 16];
    A01 += bc(v0.x); A23 += bc(v0.y);
    B01 += bc(v1.x); B23 += bc(v1.y);
    A01 += bc(v2.x); A23 += bc(v2.y);
    B01 += bc(v3.x); B23 += bc(v3.y);
    A01 += bc(v4.x); A23 += bc(v4.y);
    B01 += bc(v5.x); B23 += bc(v5.y);
    A01 += bc(v6.x); A23 += bc(v6.y);
    B01 += bc(v7.x); B23 += bc(v7.y);
}

// ---------------------------------------------------------------------------
// Kernel 2: gather-sum. 4 batch rows per block, fp16-packed transposed in
// LDS: xt[i] = uint2 = 4 fp16 = rows b0..b0+3 of column i. 32 KB LDS ->
// 4 blocks/CU, 1024 blocks x 8 waves = full occupancy. One ds_read_b64 per
// gathered index serves 4 rows; v_pk_add_f16 accumulates 2 rows/instr.
// Two features in flight per thread for independent load/gather streams.
// ---------------------------------------------------------------------------
__global__ __launch_bounds__(512, 8)
void gather_kernel(const float* __restrict__ x,
                   const unsigned int* __restrict__ cnt,
                   const uint4* __restrict__ q,      // oct-packed u16 indices
                   const unsigned short* __restrict__ q16,
                   float* __restrict__ out) {
    __shared__ uint2 xt[D_IN];                       // 32 KB
    const int tid = threadIdx.x;
    const int b0  = blockIdx.x * 4;
    const float* xb = x + (size_t)b0 * D_IN;

    // Stage 4 rows transposed + fp16 RNE packed.
    for (int c = tid; c < D_IN; c += 512) {
        float r0 = xb[c];
        float r1 = xb[c + D_IN];
        float r2 = xb[c + 2 * D_IN];
        float r3 = xb[c + 3 * D_IN];
        __half2 lo = __floats2half2_rn(r0, r1);
        __half2 hi = __floats2half2_rn(r2, r3);
        uint2 v;
        v.x = *(unsigned*)&lo;
        v.y = *(unsigned*)&hi;
        xt[c] = v;
    }
    __syncthreads();

#pragma unroll
    for (int k = 0; k < 8; k += 2) {
        const int fA = tid + k * 512;
        const int fB = fA + 512;
        int nA = (int)cnt[fA]; if (nA > MAX_SLOTS) nA = MAX_SLOTS;
        int nB = (int)cnt[fB]; if (nB > MAX_SLOTS) nB = MAX_SLOTS;
        const uint4* qA = q + fA;
        const uint4* qB = q + fB;

        h2 aA01 = {0, 0}, aA23 = {0, 0}, bA01 = {0, 0}, bA23 = {0, 0};
        h2 aB01 = {0, 0}, aB23 = {0, 0}, bB01 = {0, 0}, bB23 = {0, 0};

        const int nqA = nA >> 3, nqB = nB >> 3;
        const int jm = nqA < nqB ? nqA : nqB;
        for (int j = 0; j < jm; ++j) {
            uint4 pA = qA[(size_t)j * FEAT];         // coalesced across lanes
            uint4 pB = qB[(size_t)j * FEAT];
            do_oct(pA, xt, aA01, aA23, bA01, bA23);
            do_oct(pB, xt, aB01, aB23, bB01, bB23);
        }
        for (int j = jm; j < nqA; ++j)
            do_oct(qA[(size_t)j * FEAT], xt, aA01, aA23, bA01, bA23);
        for (int j = jm; j < nqB; ++j)
            do_oct(qB[(size_t)j * FEAT], xt, aB01, aB23, bB01, bB23);

        // tails (n & 7 leftover indices, valid entries only)
        {
            int rem = nA & 7;
            int base = (nqA * FEAT + fA) * 8;
            for (int t = 0; t < rem; ++t) {
                uint2 v = xt[q16[base + t]];
                aA01 += bc(v.x); aA23 += bc(v.y);
            }
        }
        {
            int rem = nB & 7;
            int base = (nqB * FEAT + fB) * 8;
            for (int t = 0; t < rem; ++t) {
                uint2 v = xt[q16[base + t]];
                aB01 += bc(v.x); aB23 += bc(v.y);
            }
        }

        // combine chains in fp32, store coalesced across lanes
        float* oA = out + fA;
        oA[(size_t)(b0 + 0) * FEAT] = (float)aA01[0] + (float)bA01[0];
        oA[(size_t)(b0 + 1) * FEAT] = (float)aA01[1] + (float)bA01[1];
        oA[(size_t)(b0 + 2) * FEAT] = (float)aA23[0] + (float)bA23[0];
        oA[(size_t)(b0 + 3) * FEAT] = (float)aA23[1] + (float)bA23[1];
        float* oB = out + fB;
        oB[(size_t)(b0 + 0) * FEAT] = (float)aB01[0] + (float)bB01[0];
        oB[(size_t)(b0 + 1) * FEAT] = (float)aB01[1] + (float)bB01[1];
        oB[(size_t)(b0 + 2) * FEAT] = (float)aB23[0] + (float)bB23[0];
        oB[(size_t)(b0 + 3) * FEAT] = (float)aB23[1] + (float)bB23[1];
    }
}

// ---------------------------------------------------------------------------
extern "C" void kernel_launch(void* const* d_in, const int* in_sizes, int n_in,
                              void* d_out, int out_size, void* d_ws, size_t ws_size,
                              hipStream_t stream) {
    const float* x = (const float*)d_in[0];      // (BATCH, D_IN) fp32
    const float* w = (const float*)d_in[1];      // (D_IN, FEAT)  fp32
    float* out = (float*)d_out;                  // (BATCH, FEAT) fp32

    // Workspace: [cnt: 4096 u32 = 16KB][idx: 4096*64 u16 = 512KB]
    unsigned int*   cnt = (unsigned int*)d_ws;
    unsigned short* idx = (unsigned short*)((char*)d_ws + FEAT * sizeof(unsigned int));

    hipMemsetAsync(cnt, 0, FEAT * sizeof(unsigned int), stream);

    build_lists_kernel<<<(D_IN * FEAT / 4) / 256, 256, 0, stream>>>(w, cnt, idx);

    gather_kernel<<<BATCH / 4, 512, 0, stream>>>(x, cnt, (const uint4*)idx, idx, out);
}